// Round 4
// baseline (5829.927 us; speedup 1.0000x reference)
//
#include <hip/hip_runtime.h>
#include <math.h>

#define TT 256
#define BB 32
#define EE 256
#define HH 512
#define G4 2048
#define LL 9
#define NWGD 64   // workgroups per direction in the recurrence

typedef __attribute__((ext_vector_type(8))) __bf16 bf16x8;
typedef __attribute__((ext_vector_type(4))) float f32x4;

__device__ inline ushort f2bf(float f) {
  uint u = __float_as_uint(f);
  uint r = (u + 0x7fffu + ((u >> 16) & 1u)) >> 16;
  return (ushort)r;
}
__device__ inline float bf2f(uint lo16) { return __uint_as_float(lo16 << 16); }

// ---------------- embedding gather -> bf16, time-major (T*B, E) ----------------
__global__ __launch_bounds__(256) void embed_bf16(const int* __restrict__ ids,
                                                  const float* __restrict__ emb,
                                                  ushort* __restrict__ x0) {
  int idx = blockIdx.x * 256 + threadIdx.x;   // T*B*64 = 524288 exactly
  int e4 = idx & 63;
  int tb = idx >> 6;                          // t*32 + b
  int b = tb & 31, t = tb >> 5;
  int id = ids[b * TT + t];
  float4 v = *(const float4*)(emb + (size_t)id * EE + e4 * 4);
  ushort4 o;
  o.x = f2bf(v.x); o.y = f2bf(v.y); o.z = f2bf(v.z); o.w = f2bf(v.w);
  *(ushort4*)(x0 + (size_t)tb * EE + e4 * 4) = o;
}

// ---------------- W (2048 x K) fp32 -> bf16 with gate permutation ----------------
// out row' = unit*4 + gate  <-  in row = gate*512 + unit
template <int K>
__global__ __launch_bounds__(256) void conv_perm_bf16(const float* __restrict__ in,
                                                      ushort* __restrict__ out) {
  int idx = blockIdx.x * 256 + threadIdx.x;   // over 2048*K/4
  if (idx >= 2048 * (K / 4)) return;
  int rp = idx / (K / 4);
  int c4 = (idx % (K / 4)) * 4;
  int src = (rp & 3) * 512 + (rp >> 2);
  float4 v = *(const float4*)(in + (size_t)src * K + c4);
  ushort4 o;
  o.x = f2bf(v.x); o.y = f2bf(v.y); o.z = f2bf(v.z); o.w = f2bf(v.w);
  *(ushort4*)(out + (size_t)rp * K + c4) = o;
}

// ---------------- bf16 MFMA pre-GEMM (permuted gate columns) ----------------
template <int K>
__global__ __launch_bounds__(256) void pre_gemm_mfma(const ushort* __restrict__ A,
                                                     const ushort* __restrict__ W,
                                                     const float* __restrict__ bih,
                                                     const float* __restrict__ bhh,
                                                     float* __restrict__ out) {
  __shared__ ushort As[128 * 32];
  __shared__ ushort Ws[128 * 32];
  int tid = threadIdx.x;
  int lane = tid & 63, wid = tid >> 6;
  int m0 = blockIdx.x * 128, n0 = blockIdx.y * 128;
  int wm = (wid >> 1) * 64, wn = (wid & 1) * 64;

  f32x4 acc[4][4];
#pragma unroll
  for (int i = 0; i < 4; i++)
#pragma unroll
    for (int j = 0; j < 4; j++) acc[i][j] = (f32x4){0.f, 0.f, 0.f, 0.f};

  int s1 = tid, s2 = tid + 256;
  int r1 = s1 >> 2, r2 = s2 >> 2;
  int g1 = (s1 & 3) ^ (r1 & 3);
  int g2 = (s2 & 3) ^ (r2 & 3);
  const ushort* a1 = A + (size_t)(m0 + r1) * K + g1 * 8;
  const ushort* a2 = A + (size_t)(m0 + r2) * K + g2 * 8;
  const ushort* w1 = W + (size_t)(n0 + r1) * K + g1 * 8;
  const ushort* w2 = W + (size_t)(n0 + r2) * K + g2 * 8;
  ushort* la1 = &As[(s1 & ~63) * 8];
  ushort* la2 = &As[(s2 & ~63) * 8];
  ushort* lw1 = &Ws[(s1 & ~63) * 8];
  ushort* lw2 = &Ws[(s2 & ~63) * 8];

  int ra = (lane & 15), gl = lane >> 4;

  for (int k0 = 0; k0 < K; k0 += 32) {
    __builtin_amdgcn_global_load_lds(a1 + k0, la1, 16, 0, 0);
    __builtin_amdgcn_global_load_lds(a2 + k0, la2, 16, 0, 0);
    __builtin_amdgcn_global_load_lds(w1 + k0, lw1, 16, 0, 0);
    __builtin_amdgcn_global_load_lds(w2 + k0, lw2, 16, 0, 0);
    __syncthreads();
    bf16x8 af[4], bfr[4];
#pragma unroll
    for (int f = 0; f < 4; f++) {
      int rowa = wm + f * 16 + ra;
      int ga = gl ^ (rowa & 3);
      af[f] = *(const bf16x8*)&As[rowa * 32 + ga * 8];
      int rowb = wn + f * 16 + ra;
      int gb = gl ^ (rowb & 3);
      bfr[f] = *(const bf16x8*)&Ws[rowb * 32 + gb * 8];
    }
#pragma unroll
    for (int i = 0; i < 4; i++)
#pragma unroll
      for (int j = 0; j < 4; j++)
        acc[i][j] = __builtin_amdgcn_mfma_f32_16x16x32_bf16(af[i], bfr[j], acc[i][j], 0, 0, 0);
    __syncthreads();
  }

  int cl = lane & 15, rb4 = (lane >> 4) * 4;
#pragma unroll
  for (int j = 0; j < 4; j++) {
    int col = n0 + wn + j * 16 + cl;           // permuted gate index g'
    int orig = (col & 3) * 512 + (col >> 2);   // original gate row
    float bias = bih[orig] + bhh[orig];
#pragma unroll
    for (int i = 0; i < 4; i++) {
      int mb = m0 + wm + i * 16 + rb4;
#pragma unroll
      for (int r = 0; r < 4; r++)
        out[(size_t)(mb + r) * G4 + col] = acc[i][j][r] + bias;
    }
  }
}

// ---------------- persistent MFMA bidirectional LSTM layer ----------------
// 128 WGs x 256 thr, 1 block/CU (launch_bounds min-waves=1 -> W frags stay in VGPRs).
// Slot barrier: WG w writes slots[w] = t+1 (relaxed agent store, own 128B line);
// wave 0 of every WG polls all 64 slots in parallel (lane i watches slot i).
__global__ __launch_bounds__(256, 1) void lstm_layer_mfma(
    const float* __restrict__ pre_f, const float* __restrict__ pre_r,
    const ushort* __restrict__ whhp_f, const ushort* __restrict__ whhp_r,
    ushort* __restrict__ hping, ushort* __restrict__ hpong,   // each [2][32][512] bf16
    ushort* __restrict__ xcat_bf,
    int* __restrict__ sync_base) {
  __shared__ float gs[32][33];
  int wg = blockIdx.x;
  int dir = wg >> 6;
  int wgl = wg & 63;
  const float* pre = dir ? pre_r : pre_f;
  const ushort* wp = dir ? whhp_r : whhp_f;
  int* slots = sync_base + dir * (NWGD * 32);   // 64 slots, 128B stride

  int tid = threadIdx.x;
  int lane = tid & 63, wid = tid >> 6;
  int mq = wid & 1, nq = wid >> 1;
  int cl = lane & 15, gl = lane >> 4;

  // resident B-fragments: W'[row'][k], row' = wgl*32 + nq*16 + cl, k = kt*32 + gl*8
  bf16x8 bfrag[16];
  {
    const ushort* wrow = wp + (size_t)(wgl * 32 + nq * 16 + cl) * 512 + gl * 8;
#pragma unroll
    for (int kt = 0; kt < 16; kt++) bfrag[kt] = *(const bf16x8*)(wrow + kt * 32);
  }
  int u = tid >> 5, b = tid & 31;   // epilogue role
  int ug = wgl * 8 + u;
  float creg = 0.f;
  int ab = mq * 16 + cl;

  // prime pre-activation prefetch for step 0
  float4 p4 = *(const float4*)(pre + ((size_t)(dir ? (TT - 1) : 0) * 32 + b) * G4 + ug * 4);

  for (int t = 0; t < TT; ++t) {
    int seq = dir ? (TT - 1 - t) : t;
    const ushort* hp = ((t & 1) ? hpong : hping) + dir * (32 * 512);
    ushort* hn = ((t & 1) ? hping : hpong) + dir * (32 * 512);

    // A-frags from global h (bf16), two independent MFMA chains
    const ushort* arow = hp + (size_t)ab * 512 + gl * 8;
    bf16x8 afr[16];
#pragma unroll
    for (int kt = 0; kt < 16; kt++) afr[kt] = *(const bf16x8*)(arow + kt * 32);
    f32x4 acc0 = (f32x4){0.f, 0.f, 0.f, 0.f};
    f32x4 acc1 = (f32x4){0.f, 0.f, 0.f, 0.f};
#pragma unroll
    for (int kt = 0; kt < 16; kt += 2) {
      acc0 = __builtin_amdgcn_mfma_f32_16x16x32_bf16(afr[kt], bfrag[kt], acc0, 0, 0, 0);
      acc1 = __builtin_amdgcn_mfma_f32_16x16x32_bf16(afr[kt + 1], bfrag[kt + 1], acc1, 0, 0, 0);
    }
    f32x4 acc = acc0 + acc1;

    int rb = mq * 16 + gl * 4;
    int cc = nq * 16 + cl;
#pragma unroll
    for (int r = 0; r < 4; r++) gs[rb + r][cc] = acc[r];
    __syncthreads();

    if (tid < 128) {
      float gi_ = gs[b][4 * u + 0] + p4.x;
      float gf_ = gs[b][4 * u + 1] + p4.y;
      float gg_ = gs[b][4 * u + 2] + p4.z;
      float go_ = gs[b][4 * u + 3] + p4.w;
      float si = 1.f / (1.f + __expf(-gi_));
      float sf = 1.f / (1.f + __expf(-gf_));
      float so = 1.f / (1.f + __expf(-go_));
      float tg = tanhf(gg_);
      creg = sf * creg + si * tg;
      float h = so * tanhf(creg);
      ushort h16 = f2bf(h);
      hn[b * 512 + ug] = h16;
      xcat_bf[((size_t)seq * 32 + b) * 1024 + dir * 512 + ug] = h16;
    }
    if (t == TT - 1) break;

    __syncthreads();   // all h stores issued (compiler drains vmcnt before barrier)
    if (tid == 0) {
      __threadfence();  // release: write back this XCD's L2
      __hip_atomic_store(slots + wgl * 32, t + 1, __ATOMIC_RELAXED, __HIP_MEMORY_SCOPE_AGENT);
    }
    // prefetch next step's pre-activations while waiting (independent of h)
    {
      int seqn = dir ? (TT - 2 - t) : (t + 1);
      p4 = *(const float4*)(pre + ((size_t)seqn * 32 + b) * G4 + ug * 4);
    }
    if (wid == 0) {
      int target = t + 1;
      while (true) {
        int v = __hip_atomic_load(slots + lane * 32, __ATOMIC_RELAXED, __HIP_MEMORY_SCOPE_AGENT);
        if (__all(v >= target)) break;
        __builtin_amdgcn_s_sleep(1);
      }
    }
    if (tid == 0) __threadfence();  // acquire: invalidate stale caches before reading new h
    __syncthreads();
  }
}

// ---------------- classifier from bf16 xcat ----------------
__global__ __launch_bounds__(256) void cls_kernel_bf(const ushort* __restrict__ x2,
                                                     const float* __restrict__ cw,
                                                     const float* __restrict__ cb,
                                                     float* __restrict__ em) {
  int idx = blockIdx.x * blockDim.x + threadIdx.x;
  if (idx >= BB * TT * LL) return;
  int l = idx % LL;
  int bt = idx / LL;
  int t = bt % TT;
  int b = bt / TT;
  const ushort* xr = x2 + ((size_t)t * BB + b) * 1024;
  const float* wr = cw + (size_t)l * 1024;
  float s = 0.f;
#pragma unroll 4
  for (int k = 0; k < 1024; k += 8) {
    uint4 xv = *(const uint4*)(xr + k);
    float4 wa = *(const float4*)(wr + k);
    float4 wb = *(const float4*)(wr + k + 4);
    s += bf2f(xv.x & 0xffffu) * wa.x + __uint_as_float(xv.x & 0xffff0000u) * wa.y;
    s += bf2f(xv.y & 0xffffu) * wa.z + __uint_as_float(xv.y & 0xffff0000u) * wa.w;
    s += bf2f(xv.z & 0xffffu) * wb.x + __uint_as_float(xv.z & 0xffff0000u) * wb.y;
    s += bf2f(xv.w & 0xffffu) * wb.z + __uint_as_float(xv.w & 0xffff0000u) * wb.w;
  }
  em[idx] = s + cb[l];
}

// ---------------- CRF NLL, 4 WGs x 8 batches, alpha in registers + shuffles ----------------
__global__ __launch_bounds__(128) void crf_part(const float* __restrict__ em,
                                                const int* __restrict__ labels,
                                                const int* __restrict__ mask,
                                                const float* __restrict__ start,
                                                const float* __restrict__ end,
                                                const float* __restrict__ trans,
                                                float* __restrict__ partials) {
  __shared__ float tr[81], st[9], en[9];
  int tid = threadIdx.x;
  if (tid < 81) tr[tid] = trans[tid];
  if (tid < 9) { st[tid] = start[tid]; en[tid] = end[tid]; }
  __syncthreads();
  int g = tid >> 4;            // group 0..7 (one batch per 16 lanes)
  int j = tid & 15;            // label lane
  int b = blockIdx.x * 8 + g;
  bool actj = j < 9;
  int jj9 = actj ? j : 0;

  int tg0 = labels[b * TT];
  if (tg0 == -100) tg0 = 0;
  float al = actj ? (st[j] + em[(size_t)b * TT * LL + j]) : -1e30f;
  float sc = st[tg0] + em[(size_t)b * TT * LL + tg0];
  int prev = tg0;

  // prefetch state for t = 1
  float e_j, e_tg;
  int tg_c, mk_c;
  {
    int tq = labels[b * TT + 1];
    if (tq == -100) tq = 0;
    tg_c = tq;
    mk_c = mask[b * TT + 1];
    e_j = actj ? em[((size_t)b * TT + 1) * LL + j] : 0.f;
    e_tg = em[((size_t)b * TT + 1) * LL + tq];
  }
  for (int t = 1; t < TT; t++) {
    float e = e_j, etg = e_tg;
    int tg = tg_c, mk = mk_c;
    if (t + 1 < TT) {
      int tq = labels[b * TT + t + 1];
      if (tq == -100) tq = 0;
      tg_c = tq;
      mk_c = mask[b * TT + t + 1];
      e_j = actj ? em[((size_t)b * TT + t + 1) * LL + j] : 0.f;
      e_tg = em[((size_t)b * TT + t + 1) * LL + tq];
    }
    float ai[9];
#pragma unroll
    for (int i = 0; i < 9; i++) ai[i] = __shfl(al, i, 16) + tr[i * 9 + jj9];
    float m = ai[0];
#pragma unroll
    for (int i = 1; i < 9; i++) m = fmaxf(m, ai[i]);
    float s = 0.f;
#pragma unroll
    for (int i = 0; i < 9; i++) s += __expf(ai[i] - m);
    float nxt = m + __logf(s) + e;
    if (mk && actj) al = nxt;
    if (mk && j == 0) { sc += tr[prev * 9 + tg] + etg; prev = tg; }
  }
  // logz = lse(al + en)
  float av[9];
#pragma unroll
  for (int i = 0; i < 9; i++) av[i] = __shfl(al, i, 16) + en[i];
  float m2 = av[0];
#pragma unroll
  for (int i = 1; i < 9; i++) m2 = fmaxf(m2, av[i]);
  float s2 = 0.f;
#pragma unroll
  for (int i = 0; i < 9; i++) s2 += __expf(av[i] - m2);
  float logz = m2 + __logf(s2);
  if (j == 0) partials[b] = sc + en[prev] - logz;
}

__global__ __launch_bounds__(64) void crf_final(const float* __restrict__ partials,
                                                float* __restrict__ loss) {
  int lane = threadIdx.x;
  float v = (lane < 32) ? partials[lane] : 0.f;
  for (int off = 32; off >= 1; off >>= 1) v += __shfl_down(v, off, 64);
  if (lane == 0) loss[0] = -v / 32.f;
}

extern "C" void kernel_launch(void* const* d_in, const int* in_sizes, int n_in,
                              void* d_out, int out_size, void* d_ws, size_t ws_size,
                              hipStream_t stream) {
  (void)in_sizes; (void)n_in; (void)out_size; (void)ws_size;
  const int* ids = (const int*)d_in[0];
  const int* amask = (const int*)d_in[1];
  const int* labels = (const int*)d_in[2];
  const float* emb = (const float*)d_in[3];
  const float* wih0f = (const float*)d_in[4];
  const float* whh0f = (const float*)d_in[5];
  const float* bih0f = (const float*)d_in[6];
  const float* bhh0f = (const float*)d_in[7];
  const float* wih0r = (const float*)d_in[8];
  const float* whh0r = (const float*)d_in[9];
  const float* bih0r = (const float*)d_in[10];
  const float* bhh0r = (const float*)d_in[11];
  const float* wih1f = (const float*)d_in[12];
  const float* whh1f = (const float*)d_in[13];
  const float* bih1f = (const float*)d_in[14];
  const float* bhh1f = (const float*)d_in[15];
  const float* wih1r = (const float*)d_in[16];
  const float* whh1r = (const float*)d_in[17];
  const float* bih1r = (const float*)d_in[18];
  const float* bhh1r = (const float*)d_in[19];
  const float* cls_w = (const float*)d_in[20];
  const float* cls_b = (const float*)d_in[21];
  const float* crf_s = (const float*)d_in[22];
  const float* crf_e = (const float*)d_in[23];
  const float* crf_t = (const float*)d_in[24];

  char* base = (char*)d_ws;
  int* sync0 = (int*)base;                        // 16KB (2 dirs x 64 slots x 128B)
  int* sync1 = (int*)(base + 16384);              // 16KB
  ushort* hA = (ushort*)(base + 32768);           // layer0 ping (zeroed), 64KB
  ushort* hC = hA + 32768;                        // layer1 ping (zeroed), 64KB
  ushort* hB = hC + 32768;                        // layer0 pong
  ushort* hD = hB + 32768;                        // layer1 pong
  float* partials = (float*)(hD + 32768);         // 32 floats (+pad)
  ushort* xc_bf = (ushort*)(partials + 64);       // (8192,1024) bf16
  ushort* x0bf = xc_bf + 8388608;                 // (8192,256) bf16
  ushort* wihp0f = x0bf + 2097152;
  ushort* wihp0r = wihp0f + 524288;
  ushort* wihp1f = wihp0r + 524288;
  ushort* wihp1r = wihp1f + 2097152;
  ushort* whhp0f = wihp1r + 2097152;
  ushort* whhp0r = whhp0f + 1048576;
  ushort* whhp1f = whhp0r + 1048576;
  ushort* whhp1r = whhp1f + 1048576;
  float* pref = (float*)(whhp1r + 1048576);       // (8192,2048) f32
  float* prer = pref + 16777216;

  float* loss = (float*)d_out;
  float* em = (float*)d_out + 1;

  // zero: sync0+sync1 (32KB) + hA+hC (128KB), contiguous
  hipMemsetAsync(d_ws, 0, 32768 + 131072, stream);

  embed_bf16<<<2048, 256, 0, stream>>>(ids, emb, x0bf);
  conv_perm_bf16<256><<<512, 256, 0, stream>>>(wih0f, wihp0f);
  conv_perm_bf16<256><<<512, 256, 0, stream>>>(wih0r, wihp0r);
  conv_perm_bf16<1024><<<2048, 256, 0, stream>>>(wih1f, wihp1f);
  conv_perm_bf16<1024><<<2048, 256, 0, stream>>>(wih1r, wihp1r);
  conv_perm_bf16<512><<<1024, 256, 0, stream>>>(whh0f, whhp0f);
  conv_perm_bf16<512><<<1024, 256, 0, stream>>>(whh0r, whhp0r);
  conv_perm_bf16<512><<<1024, 256, 0, stream>>>(whh1f, whhp1f);
  conv_perm_bf16<512><<<1024, 256, 0, stream>>>(whh1r, whhp1r);

  // ---- layer 0 ----
  pre_gemm_mfma<256><<<dim3(64, 16), 256, 0, stream>>>(x0bf, wihp0f, bih0f, bhh0f, pref);
  pre_gemm_mfma<256><<<dim3(64, 16), 256, 0, stream>>>(x0bf, wihp0r, bih0r, bhh0r, prer);
  {
    const float* a0 = pref; const float* a1 = prer;
    const ushort* a2 = whhp0f; const ushort* a3 = whhp0r;
    ushort* a4 = hA; ushort* a5 = hB;
    ushort* a6 = xc_bf; int* a7 = sync0;
    void* args[] = {&a0, &a1, &a2, &a3, &a4, &a5, &a6, &a7};
    hipLaunchCooperativeKernel((void*)lstm_layer_mfma, dim3(2 * NWGD), dim3(256), args, 0, stream);
  }
  // ---- layer 1 ----
  pre_gemm_mfma<1024><<<dim3(64, 16), 256, 0, stream>>>(xc_bf, wihp1f, bih1f, bhh1f, pref);
  pre_gemm_mfma<1024><<<dim3(64, 16), 256, 0, stream>>>(xc_bf, wihp1r, bih1r, bhh1r, prer);
  {
    const float* a0 = pref; const float* a1 = prer;
    const ushort* a2 = whhp1f; const ushort* a3 = whhp1r;
    ushort* a4 = hC; ushort* a5 = hD;
    ushort* a6 = xc_bf; int* a7 = sync1;
    void* args[] = {&a0, &a1, &a2, &a3, &a4, &a5, &a6, &a7};
    hipLaunchCooperativeKernel((void*)lstm_layer_mfma, dim3(2 * NWGD), dim3(256), args, 0, stream);
  }

  cls_kernel_bf<<<(BB * TT * LL + 255) / 256, 256, 0, stream>>>(xc_bf, cls_w, cls_b, em);
  crf_part<<<4, 128, 0, stream>>>(em, labels, amask, crf_s, crf_e, crf_t, partials);
  crf_final<<<1, 64, 0, stream>>>(partials, loss);
}

// Round 6
// 4578.955 us; speedup vs baseline: 1.2732x; 1.2732x over previous
//
#include <hip/hip_runtime.h>
#include <math.h>

#define TT 256
#define BB 32
#define EE 256
#define HH 512
#define G4 2048
#define LL 9
#define NWGD 64   // workgroups per direction in the recurrence

typedef __attribute__((ext_vector_type(8))) __bf16 bf16x8;
typedef __attribute__((ext_vector_type(4))) float f32x4;
typedef __attribute__((ext_vector_type(4))) uint uint32x4;
typedef __attribute__((ext_vector_type(2))) unsigned long long u64x2;

__device__ inline ushort f2bf(float f) {
  uint u = __float_as_uint(f);
  uint r = (u + 0x7fffu + ((u >> 16) & 1u)) >> 16;
  return (ushort)r;
}
__device__ inline float bf2f(uint lo16) { return __uint_as_float(lo16 << 16); }
__device__ inline void waitv0() { asm volatile("s_waitcnt vmcnt(0)" ::: "memory"); }

// device-coherent 8B ops (relaxed agent scope -> sc1, no cache maintenance)
__device__ inline void st64_dev(void* p, unsigned long long v) {
  __hip_atomic_store((unsigned long long*)p, v, __ATOMIC_RELAXED, __HIP_MEMORY_SCOPE_AGENT);
}
__device__ inline unsigned long long ld64_dev(const void* p) {
  return __hip_atomic_load((const unsigned long long*)p, __ATOMIC_RELAXED, __HIP_MEMORY_SCOPE_AGENT);
}

// ---------------- embedding gather -> bf16, time-major (T*B, E) ----------------
__global__ __launch_bounds__(256) void embed_bf16(const int* __restrict__ ids,
                                                  const float* __restrict__ emb,
                                                  ushort* __restrict__ x0) {
  int idx = blockIdx.x * 256 + threadIdx.x;   // T*B*64 = 524288 exactly
  int e4 = idx & 63;
  int tb = idx >> 6;                          // t*32 + b
  int b = tb & 31, t = tb >> 5;
  int id = ids[b * TT + t];
  float4 v = *(const float4*)(emb + (size_t)id * EE + e4 * 4);
  ushort4 o;
  o.x = f2bf(v.x); o.y = f2bf(v.y); o.z = f2bf(v.z); o.w = f2bf(v.w);
  *(ushort4*)(x0 + (size_t)tb * EE + e4 * 4) = o;
}

// ---------------- W (2048 x K) fp32 -> bf16 with gate permutation ----------------
// out row' = unit*4 + gate  <-  in row = gate*512 + unit
template <int K>
__global__ __launch_bounds__(256) void conv_perm_bf16(const float* __restrict__ in,
                                                      ushort* __restrict__ out) {
  int idx = blockIdx.x * 256 + threadIdx.x;   // over 2048*K/4
  if (idx >= 2048 * (K / 4)) return;
  int rp = idx / (K / 4);
  int c4 = (idx % (K / 4)) * 4;
  int src = (rp & 3) * 512 + (rp >> 2);
  float4 v = *(const float4*)(in + (size_t)src * K + c4);
  ushort4 o;
  o.x = f2bf(v.x); o.y = f2bf(v.y); o.z = f2bf(v.z); o.w = f2bf(v.w);
  *(ushort4*)(out + (size_t)rp * K + c4) = o;
}

// ---------------- bf16 MFMA pre-GEMM (permuted gate columns) ----------------
template <int K>
__global__ __launch_bounds__(256) void pre_gemm_mfma(const ushort* __restrict__ A,
                                                     const ushort* __restrict__ W,
                                                     const float* __restrict__ bih,
                                                     const float* __restrict__ bhh,
                                                     float* __restrict__ out) {
  __shared__ ushort As[128 * 32];
  __shared__ ushort Ws[128 * 32];
  int tid = threadIdx.x;
  int lane = tid & 63, wid = tid >> 6;
  int m0 = blockIdx.x * 128, n0 = blockIdx.y * 128;
  int wm = (wid >> 1) * 64, wn = (wid & 1) * 64;

  f32x4 acc[4][4];
#pragma unroll
  for (int i = 0; i < 4; i++)
#pragma unroll
    for (int j = 0; j < 4; j++) acc[i][j] = (f32x4){0.f, 0.f, 0.f, 0.f};

  int s1 = tid, s2 = tid + 256;
  int r1 = s1 >> 2, r2 = s2 >> 2;
  int g1 = (s1 & 3) ^ (r1 & 3);
  int g2 = (s2 & 3) ^ (r2 & 3);
  const ushort* a1 = A + (size_t)(m0 + r1) * K + g1 * 8;
  const ushort* a2 = A + (size_t)(m0 + r2) * K + g2 * 8;
  const ushort* w1 = W + (size_t)(n0 + r1) * K + g1 * 8;
  const ushort* w2 = W + (size_t)(n0 + r2) * K + g2 * 8;
  ushort* la1 = &As[(s1 & ~63) * 8];
  ushort* la2 = &As[(s2 & ~63) * 8];
  ushort* lw1 = &Ws[(s1 & ~63) * 8];
  ushort* lw2 = &Ws[(s2 & ~63) * 8];

  int ra = (lane & 15), gl = lane >> 4;

  for (int k0 = 0; k0 < K; k0 += 32) {
    __builtin_amdgcn_global_load_lds(a1 + k0, la1, 16, 0, 0);
    __builtin_amdgcn_global_load_lds(a2 + k0, la2, 16, 0, 0);
    __builtin_amdgcn_global_load_lds(w1 + k0, lw1, 16, 0, 0);
    __builtin_amdgcn_global_load_lds(w2 + k0, lw2, 16, 0, 0);
    __syncthreads();
    bf16x8 af[4], bfr[4];
#pragma unroll
    for (int f = 0; f < 4; f++) {
      int rowa = wm + f * 16 + ra;
      int ga = gl ^ (rowa & 3);
      af[f] = *(const bf16x8*)&As[rowa * 32 + ga * 8];
      int rowb = wn + f * 16 + ra;
      int gb = gl ^ (rowb & 3);
      bfr[f] = *(const bf16x8*)&Ws[rowb * 32 + gb * 8];
    }
#pragma unroll
    for (int i = 0; i < 4; i++)
#pragma unroll
      for (int j = 0; j < 4; j++)
        acc[i][j] = __builtin_amdgcn_mfma_f32_16x16x32_bf16(af[i], bfr[j], acc[i][j], 0, 0, 0);
    __syncthreads();
  }

  int cl = lane & 15, rb4 = (lane >> 4) * 4;
#pragma unroll
  for (int j = 0; j < 4; j++) {
    int col = n0 + wn + j * 16 + cl;           // permuted gate index g'
    int orig = (col & 3) * 512 + (col >> 2);   // original gate row
    float bias = bih[orig] + bhh[orig];
#pragma unroll
    for (int i = 0; i < 4; i++) {
      int mb = m0 + wm + i * 16 + rb4;
#pragma unroll
      for (int r = 0; r < 4; r++)
        out[(size_t)(mb + r) * G4 + col] = acc[i][j][r] + bias;
    }
  }
}

// ---------------- persistent MFMA bidirectional LSTM layer ----------------
// 128 WGs x 256 thr. dir = wg>>6, wgl = wg&63 -> units [wgl*8, wgl*8+8).
// h is write-once, time-indexed: step t's h IS xcat row seq(t). All recurrence-
// visible traffic (h stores, h loads, barrier slots) uses relaxed agent-scope
// atomics (sc1, coherence-point ops) -> zero buffer_wbl2/buffer_inv in the loop.
// Slot barrier: WG wgl posts slots[wgl]=t+1 after draining its h stores; wave0
// polls all 64 slots in parallel (lane i -> slot i).
__global__ __launch_bounds__(256, 1) void lstm_layer_mfma(
    const float* __restrict__ pre_f, const float* __restrict__ pre_r,
    const ushort* __restrict__ whhp_f, const ushort* __restrict__ whhp_r,
    ushort* __restrict__ xcat, int* __restrict__ sync_base) {
  __shared__ float gs[32][33];
  __shared__ __align__(16) ushort hst[32][8];
  int wg = blockIdx.x;
  int dir = wg >> 6;
  int wgl = wg & 63;
  const float* pre = dir ? pre_r : pre_f;
  const ushort* wp = dir ? whhp_r : whhp_f;
  int* slots = sync_base + dir * 128;   // 64 contiguous ints per dir, 512B apart

  int tid = threadIdx.x;
  int lane = tid & 63, wid = tid >> 6;
  int mq = wid & 1, nq = wid >> 1;
  int cl = lane & 15, gl = lane >> 4;

  // resident B-fragments: W'[row'][k], row' = wgl*32 + nq*16 + cl, k = kt*32 + gl*8.
  // ext-vector loads pinned by "+v" asm: value becomes opaque -> cannot be
  // rematerialized inside the loop (r3/r4 failure mode: VGPR_Count stuck at 52).
  uint32x4 bfragu[16];
  {
    const ushort* wrow = wp + (size_t)(wgl * 32 + nq * 16 + cl) * 512 + gl * 8;
#pragma unroll
    for (int kt = 0; kt < 16; kt++) bfragu[kt] = *(const uint32x4*)(wrow + kt * 32);
#pragma unroll
    for (int kt = 0; kt < 16; kt++) asm volatile("" : "+v"(bfragu[kt]));
  }
  int u = tid >> 5, b = tid & 31;   // epilogue role: all 256 threads (8 units x 32 b)
  int ug = wgl * 8 + u;
  float creg = 0.f;
  int ab = mq * 16 + cl;

  // prime pre-activation prefetch for step 0
  float4 p4 = *(const float4*)(pre + ((size_t)(dir ? (TT - 1) : 0) * 32 + b) * G4 + ug * 4);

  for (int t = 0; t < TT; ++t) {
    int seq = dir ? (TT - 1 - t) : t;
    f32x4 acc0 = (f32x4){0.f, 0.f, 0.f, 0.f};
    f32x4 acc1 = (f32x4){0.f, 0.f, 0.f, 0.f};
    if (t > 0) {
      int seqp = dir ? (seq + 1) : (seq - 1);   // previous step's seq
      const ushort* arow = xcat + ((size_t)seqp * 32 + ab) * 1024 + dir * 512 + gl * 8;
      bf16x8 afr[16];
#pragma unroll
      for (int kt = 0; kt < 16; kt++) {
        u64x2 w;
        w.x = ld64_dev(arow + kt * 32);
        w.y = ld64_dev(arow + kt * 32 + 4);
        afr[kt] = __builtin_bit_cast(bf16x8, w);
      }
#pragma unroll
      for (int kt = 0; kt < 16; kt += 2) {
        acc0 = __builtin_amdgcn_mfma_f32_16x16x32_bf16(
            afr[kt], __builtin_bit_cast(bf16x8, bfragu[kt]), acc0, 0, 0, 0);
        acc1 = __builtin_amdgcn_mfma_f32_16x16x32_bf16(
            afr[kt + 1], __builtin_bit_cast(bf16x8, bfragu[kt + 1]), acc1, 0, 0, 0);
      }
    }
    f32x4 acc = acc0 + acc1;

    int rb = mq * 16 + gl * 4;
    int cc = nq * 16 + cl;
#pragma unroll
    for (int r = 0; r < 4; r++) gs[rb + r][cc] = acc[r];
    __syncthreads();   // S1: gs ready

    // epilogue: thread (u,b), all 256 threads
    float gi_ = gs[b][4 * u + 0] + p4.x;
    float gf_ = gs[b][4 * u + 1] + p4.y;
    float gg_ = gs[b][4 * u + 2] + p4.z;
    float go_ = gs[b][4 * u + 3] + p4.w;
    float si = 1.f / (1.f + __expf(-gi_));
    float sf = 1.f / (1.f + __expf(-gf_));
    float so = 1.f / (1.f + __expf(-go_));
    float tg = tanhf(gg_);
    creg = sf * creg + si * tg;
    float h = so * tanhf(creg);
    hst[b][u] = f2bf(h);
    // prefetch next step's pre-activations (independent of h)
    if (t < TT - 1) {
      int seqn = dir ? (seq - 1) : (seq + 1);
      p4 = *(const float4*)(pre + ((size_t)seqn * 32 + b) * G4 + ug * 4);
    }
    __syncthreads();   // S2: hst complete

    if (tid < 32) {
      // one 16B row per lane, as 2x8B device-coherent stores
      const unsigned long long* hv = (const unsigned long long*)&hst[tid][0];
      ushort* dst = xcat + ((size_t)seq * 32 + tid) * 1024 + dir * 512 + wgl * 8;
      st64_dev(dst, hv[0]);
      st64_dev(dst + 4, hv[1]);
    }
    if (t == TT - 1) break;
    if (wid == 0) {
      waitv0();   // wave0's h stores acked at the coherence point
      if (tid == 0)
        __hip_atomic_store(slots + wgl, t + 1, __ATOMIC_RELAXED, __HIP_MEMORY_SCOPE_AGENT);
      while (true) {
        int v = __hip_atomic_load(slots + lane, __ATOMIC_RELAXED, __HIP_MEMORY_SCOPE_AGENT);
        if (__all(v >= t + 1)) break;
        __builtin_amdgcn_s_sleep(1);
      }
    }
    __syncthreads();   // S3: all 64 WGs' h_t visible -> safe to read A-frags
  }
}

// ---------------- classifier from bf16 xcat ----------------
__global__ __launch_bounds__(256) void cls_kernel_bf(const ushort* __restrict__ x2,
                                                     const float* __restrict__ cw,
                                                     const float* __restrict__ cb,
                                                     float* __restrict__ em) {
  int idx = blockIdx.x * blockDim.x + threadIdx.x;
  if (idx >= BB * TT * LL) return;
  int l = idx % LL;
  int bt = idx / LL;
  int t = bt % TT;
  int b = bt / TT;
  const ushort* xr = x2 + ((size_t)t * BB + b) * 1024;
  const float* wr = cw + (size_t)l * 1024;
  float s = 0.f;
#pragma unroll 4
  for (int k = 0; k < 1024; k += 8) {
    uint4 xv = *(const uint4*)(xr + k);
    float4 wa = *(const float4*)(wr + k);
    float4 wb = *(const float4*)(wr + k + 4);
    s += bf2f(xv.x & 0xffffu) * wa.x + __uint_as_float(xv.x & 0xffff0000u) * wa.y;
    s += bf2f(xv.y & 0xffffu) * wa.z + __uint_as_float(xv.y & 0xffff0000u) * wa.w;
    s += bf2f(xv.z & 0xffffu) * wb.x + __uint_as_float(xv.z & 0xffff0000u) * wb.y;
    s += bf2f(xv.w & 0xffffu) * wb.z + __uint_as_float(xv.w & 0xffff0000u) * wb.w;
  }
  em[idx] = s + cb[l];
}

// ---------------- CRF NLL, 4 WGs x 8 batches, alpha in registers + shuffles ----------------
__global__ __launch_bounds__(128) void crf_part(const float* __restrict__ em,
                                                const int* __restrict__ labels,
                                                const int* __restrict__ mask,
                                                const float* __restrict__ start,
                                                const float* __restrict__ end,
                                                const float* __restrict__ trans,
                                                float* __restrict__ partials) {
  __shared__ float tr[81], st[9], en[9];
  int tid = threadIdx.x;
  if (tid < 81) tr[tid] = trans[tid];
  if (tid < 9) { st[tid] = start[tid]; en[tid] = end[tid]; }
  __syncthreads();
  int g = tid >> 4;            // group 0..7 (one batch per 16 lanes)
  int j = tid & 15;            // label lane
  int b = blockIdx.x * 8 + g;
  bool actj = j < 9;
  int jj9 = actj ? j : 0;

  int tg0 = labels[b * TT];
  if (tg0 == -100) tg0 = 0;
  float al = actj ? (st[j] + em[(size_t)b * TT * LL + j]) : -1e30f;
  float sc = st[tg0] + em[(size_t)b * TT * LL + tg0];
  int prev = tg0;

  float e_j, e_tg;
  int tg_c, mk_c;
  {
    int tq = labels[b * TT + 1];
    if (tq == -100) tq = 0;
    tg_c = tq;
    mk_c = mask[b * TT + 1];
    e_j = actj ? em[((size_t)b * TT + 1) * LL + j] : 0.f;
    e_tg = em[((size_t)b * TT + 1) * LL + tq];
  }
  for (int t = 1; t < TT; t++) {
    float e = e_j, etg = e_tg;
    int tg = tg_c, mk = mk_c;
    if (t + 1 < TT) {
      int tq = labels[b * TT + t + 1];
      if (tq == -100) tq = 0;
      tg_c = tq;
      mk_c = mask[b * TT + t + 1];
      e_j = actj ? em[((size_t)b * TT + t + 1) * LL + j] : 0.f;
      e_tg = em[((size_t)b * TT + t + 1) * LL + tq];
    }
    float ai[9];
#pragma unroll
    for (int i = 0; i < 9; i++) ai[i] = __shfl(al, i, 16) + tr[i * 9 + jj9];
    float m = ai[0];
#pragma unroll
    for (int i = 1; i < 9; i++) m = fmaxf(m, ai[i]);
    float s = 0.f;
#pragma unroll
    for (int i = 0; i < 9; i++) s += __expf(ai[i] - m);
    float nxt = m + __logf(s) + e;
    if (mk && actj) al = nxt;
    if (mk && j == 0) { sc += tr[prev * 9 + tg] + etg; prev = tg; }
  }
  float av[9];
#pragma unroll
  for (int i = 0; i < 9; i++) av[i] = __shfl(al, i, 16) + en[i];
  float m2 = av[0];
#pragma unroll
  for (int i = 1; i < 9; i++) m2 = fmaxf(m2, av[i]);
  float s2 = 0.f;
#pragma unroll
  for (int i = 0; i < 9; i++) s2 += __expf(av[i] - m2);
  float logz = m2 + __logf(s2);
  if (j == 0) partials[b] = sc + en[prev] - logz;
}

__global__ __launch_bounds__(64) void crf_final(const float* __restrict__ partials,
                                                float* __restrict__ loss) {
  int lane = threadIdx.x;
  float v = (lane < 32) ? partials[lane] : 0.f;
  for (int off = 32; off >= 1; off >>= 1) v += __shfl_down(v, off, 64);
  if (lane == 0) loss[0] = -v / 32.f;
}

extern "C" void kernel_launch(void* const* d_in, const int* in_sizes, int n_in,
                              void* d_out, int out_size, void* d_ws, size_t ws_size,
                              hipStream_t stream) {
  (void)in_sizes; (void)n_in; (void)out_size; (void)ws_size;
  const int* ids = (const int*)d_in[0];
  const int* amask = (const int*)d_in[1];
  const int* labels = (const int*)d_in[2];
  const float* emb = (const float*)d_in[3];
  const float* wih0f = (const float*)d_in[4];
  const float* whh0f = (const float*)d_in[5];
  const float* bih0f = (const float*)d_in[6];
  const float* bhh0f = (const float*)d_in[7];
  const float* wih0r = (const float*)d_in[8];
  const float* whh0r = (const float*)d_in[9];
  const float* bih0r = (const float*)d_in[10];
  const float* bhh0r = (const float*)d_in[11];
  const float* wih1f = (const float*)d_in[12];
  const float* whh1f = (const float*)d_in[13];
  const float* bih1f = (const float*)d_in[14];
  const float* bhh1f = (const float*)d_in[15];
  const float* wih1r = (const float*)d_in[16];
  const float* whh1r = (const float*)d_in[17];
  const float* bih1r = (const float*)d_in[18];
  const float* bhh1r = (const float*)d_in[19];
  const float* cls_w = (const float*)d_in[20];
  const float* cls_b = (const float*)d_in[21];
  const float* crf_s = (const float*)d_in[22];
  const float* crf_e = (const float*)d_in[23];
  const float* crf_t = (const float*)d_in[24];

  char* base = (char*)d_ws;
  int* sync0 = (int*)base;                        // 2 dirs x 64 slots (contig), 2KB
  int* sync1 = (int*)(base + 2048);               // 2KB
  float* partials = (float*)(base + 4096);        // 32 floats
  ushort* xc1 = (ushort*)(base + 8192);           // (8192,1024) bf16, layer0 h (write-once)
  ushort* xc2 = xc1 + 8388608;                    // (8192,1024) bf16, layer1 h
  ushort* x0bf = xc2 + 8388608;                   // (8192,256) bf16
  ushort* wihp0f = x0bf + 2097152;
  ushort* wihp0r = wihp0f + 524288;
  ushort* wihp1f = wihp0r + 524288;
  ushort* wihp1r = wihp1f + 2097152;
  ushort* whhp0f = wihp1r + 2097152;
  ushort* whhp0r = whhp0f + 1048576;
  ushort* whhp1f = whhp0r + 1048576;
  ushort* whhp1r = whhp1f + 1048576;
  float* pref = (float*)(whhp1r + 1048576);       // (8192,2048) f32
  float* prer = pref + 16777216;

  float* loss = (float*)d_out;
  float* em = (float*)d_out + 1;

  // zero the barrier slots only (h needs no init: t=0 skips the MFMA)
  hipMemsetAsync(d_ws, 0, 4096, stream);

  embed_bf16<<<2048, 256, 0, stream>>>(ids, emb, x0bf);
  conv_perm_bf16<256><<<512, 256, 0, stream>>>(wih0f, wihp0f);
  conv_perm_bf16<256><<<512, 256, 0, stream>>>(wih0r, wihp0r);
  conv_perm_bf16<1024><<<2048, 256, 0, stream>>>(wih1f, wihp1f);
  conv_perm_bf16<1024><<<2048, 256, 0, stream>>>(wih1r, wihp1r);
  conv_perm_bf16<512><<<1024, 256, 0, stream>>>(whh0f, whhp0f);
  conv_perm_bf16<512><<<1024, 256, 0, stream>>>(whh0r, whhp0r);
  conv_perm_bf16<512><<<1024, 256, 0, stream>>>(whh1f, whhp1f);
  conv_perm_bf16<512><<<1024, 256, 0, stream>>>(whh1r, whhp1r);

  // ---- layer 0 ----
  pre_gemm_mfma<256><<<dim3(64, 16), 256, 0, stream>>>(x0bf, wihp0f, bih0f, bhh0f, pref);
  pre_gemm_mfma<256><<<dim3(64, 16), 256, 0, stream>>>(x0bf, wihp0r, bih0r, bhh0r, prer);
  {
    const float* a0 = pref; const float* a1 = prer;
    const ushort* a2 = whhp0f; const ushort* a3 = whhp0r;
    ushort* a4 = xc1; int* a5 = sync0;
    void* args[] = {&a0, &a1, &a2, &a3, &a4, &a5};
    (void)hipLaunchCooperativeKernel((void*)lstm_layer_mfma, dim3(2 * NWGD), dim3(256), args, 0, stream);
  }
  // ---- layer 1 ----
  pre_gemm_mfma<1024><<<dim3(64, 16), 256, 0, stream>>>(xc1, wihp1f, bih1f, bhh1f, pref);
  pre_gemm_mfma<1024><<<dim3(64, 16), 256, 0, stream>>>(xc1, wihp1r, bih1r, bhh1r, prer);
  {
    const float* a0 = pref; const float* a1 = prer;
    const ushort* a2 = whhp1f; const ushort* a3 = whhp1r;
    ushort* a4 = xc2; int* a5 = sync1;
    void* args[] = {&a0, &a1, &a2, &a3, &a4, &a5};
    (void)hipLaunchCooperativeKernel((void*)lstm_layer_mfma, dim3(2 * NWGD), dim3(256), args, 0, stream);
  }

  cls_kernel_bf<<<(BB * TT * LL + 255) / 256, 256, 0, stream>>>(xc2, cls_w, cls_b, em);
  crf_part<<<4, 128, 0, stream>>>(em, labels, amask, crf_s, crf_e, crf_t, partials);
  crf_final<<<1, 64, 0, stream>>>(partials, loss);
}

// Round 8
// 3392.936 us; speedup vs baseline: 1.7183x; 1.3496x over previous
//
#include <hip/hip_runtime.h>
#include <math.h>

#define TT 256
#define BB 32
#define EE 256
#define HH 512
#define G4 2048
#define LL 9
#define NWGD 64   // workgroups per direction in the recurrence

typedef __attribute__((ext_vector_type(8))) __bf16 bf16x8;
typedef __attribute__((ext_vector_type(4))) float f32x4;
typedef __attribute__((ext_vector_type(4))) uint uint32x4;

__device__ inline ushort f2bf(float f) {
  uint u = __float_as_uint(f);
  uint r = (u + 0x7fffu + ((u >> 16) & 1u)) >> 16;
  return (ushort)r;
}
__device__ inline float bf2f(uint lo16) { return __uint_as_float(lo16 << 16); }
__device__ inline void waitv0() { asm volatile("s_waitcnt vmcnt(0)" ::: "memory"); }

// overflow-safe fast tanh: tanh(x) = sign(x) * (1 - 2/(e^{2|x|}+1))
__device__ inline float fast_tanh(float x) {
  float ax = __builtin_fabsf(x);
  float e = __expf(2.f * ax);          // inf for large ax -> t = 1
  float t = 1.f - 2.f / (e + 1.f);
  return x < 0.f ? -t : t;
}

// device-coherent 8B store (relaxed agent scope -> sc1, no cache maintenance)
__device__ inline void st64_dev(void* p, unsigned long long v) {
  __hip_atomic_store((unsigned long long*)p, v, __ATOMIC_RELAXED, __HIP_MEMORY_SCOPE_AGENT);
}

// ---------------- embedding gather -> bf16, time-major (T*B, E) ----------------
__global__ __launch_bounds__(256) void embed_bf16(const int* __restrict__ ids,
                                                  const float* __restrict__ emb,
                                                  ushort* __restrict__ x0) {
  int idx = blockIdx.x * 256 + threadIdx.x;   // T*B*64 = 524288 exactly
  int e4 = idx & 63;
  int tb = idx >> 6;                          // t*32 + b
  int b = tb & 31, t = tb >> 5;
  int id = ids[b * TT + t];
  float4 v = *(const float4*)(emb + (size_t)id * EE + e4 * 4);
  ushort4 o;
  o.x = f2bf(v.x); o.y = f2bf(v.y); o.z = f2bf(v.z); o.w = f2bf(v.w);
  *(ushort4*)(x0 + (size_t)tb * EE + e4 * 4) = o;
}

// ---------------- W (2048 x K) fp32 -> bf16 with gate permutation ----------------
// out row' = unit*4 + gate  <-  in row = gate*512 + unit
template <int K>
__global__ __launch_bounds__(256) void conv_perm_bf16(const float* __restrict__ in,
                                                      ushort* __restrict__ out) {
  int idx = blockIdx.x * 256 + threadIdx.x;   // over 2048*K/4
  if (idx >= 2048 * (K / 4)) return;
  int rp = idx / (K / 4);
  int c4 = (idx % (K / 4)) * 4;
  int src = (rp & 3) * 512 + (rp >> 2);
  float4 v = *(const float4*)(in + (size_t)src * K + c4);
  ushort4 o;
  o.x = f2bf(v.x); o.y = f2bf(v.y); o.z = f2bf(v.z); o.w = f2bf(v.w);
  *(ushort4*)(out + (size_t)rp * K + c4) = o;
}

// ---------------- bf16 MFMA pre-GEMM (permuted gate columns) ----------------
template <int K>
__global__ __launch_bounds__(256) void pre_gemm_mfma(const ushort* __restrict__ A,
                                                     const ushort* __restrict__ W,
                                                     const float* __restrict__ bih,
                                                     const float* __restrict__ bhh,
                                                     float* __restrict__ out) {
  __shared__ ushort As[128 * 32];
  __shared__ ushort Ws[128 * 32];
  int tid = threadIdx.x;
  int lane = tid & 63, wid = tid >> 6;
  int m0 = blockIdx.x * 128, n0 = blockIdx.y * 128;
  int wm = (wid >> 1) * 64, wn = (wid & 1) * 64;

  f32x4 acc[4][4];
#pragma unroll
  for (int i = 0; i < 4; i++)
#pragma unroll
    for (int j = 0; j < 4; j++) acc[i][j] = (f32x4){0.f, 0.f, 0.f, 0.f};

  int s1 = tid, s2 = tid + 256;
  int r1 = s1 >> 2, r2 = s2 >> 2;
  int g1 = (s1 & 3) ^ (r1 & 3);
  int g2 = (s2 & 3) ^ (r2 & 3);
  const ushort* a1 = A + (size_t)(m0 + r1) * K + g1 * 8;
  const ushort* a2 = A + (size_t)(m0 + r2) * K + g2 * 8;
  const ushort* w1 = W + (size_t)(n0 + r1) * K + g1 * 8;
  const ushort* w2 = W + (size_t)(n0 + r2) * K + g2 * 8;
  ushort* la1 = &As[(s1 & ~63) * 8];
  ushort* la2 = &As[(s2 & ~63) * 8];
  ushort* lw1 = &Ws[(s1 & ~63) * 8];
  ushort* lw2 = &Ws[(s2 & ~63) * 8];

  int ra = (lane & 15), gl = lane >> 4;

  for (int k0 = 0; k0 < K; k0 += 32) {
    __builtin_amdgcn_global_load_lds(a1 + k0, la1, 16, 0, 0);
    __builtin_amdgcn_global_load_lds(a2 + k0, la2, 16, 0, 0);
    __builtin_amdgcn_global_load_lds(w1 + k0, lw1, 16, 0, 0);
    __builtin_amdgcn_global_load_lds(w2 + k0, lw2, 16, 0, 0);
    __syncthreads();
    bf16x8 af[4], bfr[4];
#pragma unroll
    for (int f = 0; f < 4; f++) {
      int rowa = wm + f * 16 + ra;
      int ga = gl ^ (rowa & 3);
      af[f] = *(const bf16x8*)&As[rowa * 32 + ga * 8];
      int rowb = wn + f * 16 + ra;
      int gb = gl ^ (rowb & 3);
      bfr[f] = *(const bf16x8*)&Ws[rowb * 32 + gb * 8];
    }
#pragma unroll
    for (int i = 0; i < 4; i++)
#pragma unroll
      for (int j = 0; j < 4; j++)
        acc[i][j] = __builtin_amdgcn_mfma_f32_16x16x32_bf16(af[i], bfr[j], acc[i][j], 0, 0, 0);
    __syncthreads();
  }

  int cl = lane & 15, rb4 = (lane >> 4) * 4;
#pragma unroll
  for (int j = 0; j < 4; j++) {
    int col = n0 + wn + j * 16 + cl;           // permuted gate index g'
    int orig = (col & 3) * 512 + (col >> 2);   // original gate row
    float bias = bih[orig] + bhh[orig];
#pragma unroll
    for (int i = 0; i < 4; i++) {
      int mb = m0 + wm + i * 16 + rb4;
#pragma unroll
      for (int r = 0; r < 4; r++)
        out[(size_t)(mb + r) * G4 + col] = acc[i][j][r] + bias;
    }
  }
}

// ---------------- persistent MFMA bidirectional LSTM layer ----------------
// 128 WGs x 256 thr. dir = wg>>6, wgl = wg&63 -> units [wgl*8, wgl*8+8).
// W'hh slice (32 rows x 512) lives in LDS (padded stride 520 -> uniform banks).
// h is write-once, time-indexed: step t's h IS xcat row seq(t). Producers store h
// with sc1 (LLC write-through) + vmcnt drain, then post a slot; consumers read h
// with PLAIN vector loads (safe: address written exactly once, never cached
// pre-write; XCD-local L2 then shares the fetch across its WGs).
__global__ __launch_bounds__(256, 1) void lstm_layer_mfma(
    const float* __restrict__ pre_f, const float* __restrict__ pre_r,
    const ushort* __restrict__ whhp_f, const ushort* __restrict__ whhp_r,
    ushort* __restrict__ xcat, int* __restrict__ sync_base) {
  __shared__ float gs[32][33];
  __shared__ __align__(16) ushort hst[32][8];
  __shared__ __align__(16) ushort wlds[32 * 520];   // 33.3 KB
  int wg = blockIdx.x;
  int dir = wg >> 6;
  int wgl = wg & 63;
  const float* pre = dir ? pre_r : pre_f;
  const ushort* wp = dir ? whhp_r : whhp_f;
  int* slots = sync_base + dir * 128;   // 64 contiguous ints per dir, 512B apart

  int tid = threadIdx.x;
  int lane = tid & 63, wid = tid >> 6;
  int mq = wid & 1, nq = wid >> 1;
  int cl = lane & 15, gl = lane >> 4;

  // stage W' slice into LDS: 32 rows x 512, row stride 520 ushorts
  for (int i = tid; i < 2048; i += 256) {
    int row = i >> 6;
    int c8 = (i & 63) * 8;
    uint32x4 v = *(const uint32x4*)(wp + (size_t)(wgl * 32 + row) * 512 + c8);
    *(uint32x4*)&wlds[row * 520 + c8] = v;
  }
  __syncthreads();

  int u = tid >> 5, b = tid & 31;   // epilogue role: all 256 threads (8 units x 32 b)
  int ug = wgl * 8 + u;
  float creg = 0.f;
  int ab = mq * 16 + cl;            // A-frag batch row
  const ushort* wbase = &wlds[(nq * 16 + cl) * 520 + gl * 8];

  // prime pre-activation prefetch for step 0
  float4 p4 = *(const float4*)(pre + ((size_t)(dir ? (TT - 1) : 0) * 32 + b) * G4 + ug * 4);

  for (int t = 0; t < TT; ++t) {
    int seq = dir ? (TT - 1 - t) : t;
    f32x4 acc0 = (f32x4){0.f, 0.f, 0.f, 0.f};
    f32x4 acc1 = (f32x4){0.f, 0.f, 0.f, 0.f};
    if (t > 0) {
      int seqp = dir ? (seq + 1) : (seq - 1);   // previous step's seq
      const ushort* arow = xcat + ((size_t)seqp * 32 + ab) * 1024 + dir * 512 + gl * 8;
      bf16x8 afr[16];
#pragma unroll
      for (int kt = 0; kt < 16; kt++) afr[kt] = *(const bf16x8*)(arow + kt * 32);
#pragma unroll
      for (int kt = 0; kt < 16; kt += 2) {
        bf16x8 wf0 = *(const bf16x8*)(wbase + kt * 32);
        bf16x8 wf1 = *(const bf16x8*)(wbase + (kt + 1) * 32);
        acc0 = __builtin_amdgcn_mfma_f32_16x16x32_bf16(afr[kt], wf0, acc0, 0, 0, 0);
        acc1 = __builtin_amdgcn_mfma_f32_16x16x32_bf16(afr[kt + 1], wf1, acc1, 0, 0, 0);
      }
    }
    f32x4 acc = acc0 + acc1;

    int rb = mq * 16 + gl * 4;
    int cc = nq * 16 + cl;
#pragma unroll
    for (int r = 0; r < 4; r++) gs[rb + r][cc] = acc[r];
    __syncthreads();   // S1: gs ready

    // epilogue: thread (u,b), all 256 threads
    float gi_ = gs[b][4 * u + 0] + p4.x;
    float gf_ = gs[b][4 * u + 1] + p4.y;
    float gg_ = gs[b][4 * u + 2] + p4.z;
    float go_ = gs[b][4 * u + 3] + p4.w;
    float si = 1.f / (1.f + __expf(-gi_));
    float sf = 1.f / (1.f + __expf(-gf_));
    float so = 1.f / (1.f + __expf(-go_));
    float tg = fast_tanh(gg_);
    creg = sf * creg + si * tg;
    float h = so * fast_tanh(creg);
    hst[b][u] = f2bf(h);
    // prefetch next step's pre-activations (independent of h, overlaps barrier)
    if (t < TT - 1) {
      int seqn = dir ? (seq - 1) : (seq + 1);
      p4 = *(const float4*)(pre + ((size_t)seqn * 32 + b) * G4 + ug * 4);
    }
    __syncthreads();   // S2: hst complete

    if (tid < 32) {
      // one 16B row chunk per lane, as 2x8B device-coherent stores
      const unsigned long long* hv = (const unsigned long long*)&hst[tid][0];
      ushort* dst = xcat + ((size_t)seq * 32 + tid) * 1024 + dir * 512 + wgl * 8;
      st64_dev(dst, hv[0]);
      st64_dev(dst + 4, hv[1]);
    }
    if (t == TT - 1) break;
    if (wid == 0) {
      waitv0();   // wave0's h stores acked at the coherence point
      if (tid == 0)
        __hip_atomic_store(slots + wgl, t + 1, __ATOMIC_RELAXED, __HIP_MEMORY_SCOPE_AGENT);
      while (true) {
        int v = __hip_atomic_load(slots + lane, __ATOMIC_RELAXED, __HIP_MEMORY_SCOPE_AGENT);
        if (__all(v >= t + 1)) break;
        __builtin_amdgcn_s_sleep(1);
      }
      asm volatile("" ::: "memory");   // no hoisting of h loads above the poll
    }
    __syncthreads();   // S3: all 64 WGs' h_t visible -> safe to read A-frags
  }
}

// ---------------- classifier from bf16 xcat ----------------
__global__ __launch_bounds__(256) void cls_kernel_bf(const ushort* __restrict__ x2,
                                                     const float* __restrict__ cw,
                                                     const float* __restrict__ cb,
                                                     float* __restrict__ em) {
  int idx = blockIdx.x * blockDim.x + threadIdx.x;
  if (idx >= BB * TT * LL) return;
  int l = idx % LL;
  int bt = idx / LL;
  int t = bt % TT;
  int b = bt / TT;
  const ushort* xr = x2 + ((size_t)t * BB + b) * 1024;
  const float* wr = cw + (size_t)l * 1024;
  float s = 0.f;
#pragma unroll 4
  for (int k = 0; k < 1024; k += 8) {
    uint4 xv = *(const uint4*)(xr + k);
    float4 wa = *(const float4*)(wr + k);
    float4 wb = *(const float4*)(wr + k + 4);
    s += bf2f(xv.x & 0xffffu) * wa.x + __uint_as_float(xv.x & 0xffff0000u) * wa.y;
    s += bf2f(xv.y & 0xffffu) * wa.z + __uint_as_float(xv.y & 0xffff0000u) * wa.w;
    s += bf2f(xv.z & 0xffffu) * wb.x + __uint_as_float(xv.z & 0xffff0000u) * wb.y;
    s += bf2f(xv.w & 0xffffu) * wb.z + __uint_as_float(xv.w & 0xffff0000u) * wb.w;
  }
  em[idx] = s + cb[l];
}

// ---------------- CRF NLL, 4 WGs x 8 batches, alpha in registers + shuffles ----------------
__global__ __launch_bounds__(128) void crf_part(const float* __restrict__ em,
                                                const int* __restrict__ labels,
                                                const int* __restrict__ mask,
                                                const float* __restrict__ start,
                                                const float* __restrict__ end,
                                                const float* __restrict__ trans,
                                                float* __restrict__ partials) {
  __shared__ float tr[81], st[9], en[9];
  int tid = threadIdx.x;
  if (tid < 81) tr[tid] = trans[tid];
  if (tid < 9) { st[tid] = start[tid]; en[tid] = end[tid]; }
  __syncthreads();
  int g = tid >> 4;            // group 0..7 (one batch per 16 lanes)
  int j = tid & 15;            // label lane
  int b = blockIdx.x * 8 + g;
  bool actj = j < 9;
  int jj9 = actj ? j : 0;

  int tg0 = labels[b * TT];
  if (tg0 == -100) tg0 = 0;
  float al = actj ? (st[j] + em[(size_t)b * TT * LL + j]) : -1e30f;
  float sc = st[tg0] + em[(size_t)b * TT * LL + tg0];
  int prev = tg0;

  float e_j, e_tg;
  int tg_c, mk_c;
  {
    int tq = labels[b * TT + 1];
    if (tq == -100) tq = 0;
    tg_c = tq;
    mk_c = mask[b * TT + 1];
    e_j = actj ? em[((size_t)b * TT + 1) * LL + j] : 0.f;
    e_tg = em[((size_t)b * TT + 1) * LL + tq];
  }
  for (int t = 1; t < TT; t++) {
    float e = e_j, etg = e_tg;
    int tg = tg_c, mk = mk_c;
    if (t + 1 < TT) {
      int tq = labels[b * TT + t + 1];
      if (tq == -100) tq = 0;
      tg_c = tq;
      mk_c = mask[b * TT + t + 1];
      e_j = actj ? em[((size_t)b * TT + t + 1) * LL + j] : 0.f;
      e_tg = em[((size_t)b * TT + t + 1) * LL + tq];
    }
    float ai[9];
#pragma unroll
    for (int i = 0; i < 9; i++) ai[i] = __shfl(al, i, 16) + tr[i * 9 + jj9];
    float m = ai[0];
#pragma unroll
    for (int i = 1; i < 9; i++) m = fmaxf(m, ai[i]);
    float s = 0.f;
#pragma unroll
    for (int i = 0; i < 9; i++) s += __expf(ai[i] - m);
    float nxt = m + __logf(s) + e;
    if (mk && actj) al = nxt;
    if (mk && j == 0) { sc += tr[prev * 9 + tg] + etg; prev = tg; }
  }
  float av[9];
#pragma unroll
  for (int i = 0; i < 9; i++) av[i] = __shfl(al, i, 16) + en[i];
  float m2 = av[0];
#pragma unroll
  for (int i = 1; i < 9; i++) m2 = fmaxf(m2, av[i]);
  float s2 = 0.f;
#pragma unroll
  for (int i = 0; i < 9; i++) s2 += __expf(av[i] - m2);
  float logz = m2 + __logf(s2);
  if (j == 0) partials[b] = sc + en[prev] - logz;
}

__global__ __launch_bounds__(64) void crf_final(const float* __restrict__ partials,
                                                float* __restrict__ loss) {
  int lane = threadIdx.x;
  float v = (lane < 32) ? partials[lane] : 0.f;
  for (int off = 32; off >= 1; off >>= 1) v += __shfl_down(v, off, 64);
  if (lane == 0) loss[0] = -v / 32.f;
}

extern "C" void kernel_launch(void* const* d_in, const int* in_sizes, int n_in,
                              void* d_out, int out_size, void* d_ws, size_t ws_size,
                              hipStream_t stream) {
  (void)in_sizes; (void)n_in; (void)out_size; (void)ws_size;
  const int* ids = (const int*)d_in[0];
  const int* amask = (const int*)d_in[1];
  const int* labels = (const int*)d_in[2];
  const float* emb = (const float*)d_in[3];
  const float* wih0f = (const float*)d_in[4];
  const float* whh0f = (const float*)d_in[5];
  const float* bih0f = (const float*)d_in[6];
  const float* bhh0f = (const float*)d_in[7];
  const float* wih0r = (const float*)d_in[8];
  const float* whh0r = (const float*)d_in[9];
  const float* bih0r = (const float*)d_in[10];
  const float* bhh0r = (const float*)d_in[11];
  const float* wih1f = (const float*)d_in[12];
  const float* whh1f = (const float*)d_in[13];
  const float* bih1f = (const float*)d_in[14];
  const float* bhh1f = (const float*)d_in[15];
  const float* wih1r = (const float*)d_in[16];
  const float* whh1r = (const float*)d_in[17];
  const float* bih1r = (const float*)d_in[18];
  const float* bhh1r = (const float*)d_in[19];
  const float* cls_w = (const float*)d_in[20];
  const float* cls_b = (const float*)d_in[21];
  const float* crf_s = (const float*)d_in[22];
  const float* crf_e = (const float*)d_in[23];
  const float* crf_t = (const float*)d_in[24];

  char* base = (char*)d_ws;
  int* sync0 = (int*)base;                        // 2 dirs x 64 slots (contig), 2KB
  int* sync1 = (int*)(base + 2048);               // 2KB
  float* partials = (float*)(base + 4096);        // 32 floats
  ushort* xc1 = (ushort*)(base + 8192);           // (8192,1024) bf16, layer0 h (write-once)
  ushort* xc2 = xc1 + 8388608;                    // (8192,1024) bf16, layer1 h
  ushort* x0bf = xc2 + 8388608;                   // (8192,256) bf16
  ushort* wihp0f = x0bf + 2097152;
  ushort* wihp0r = wihp0f + 524288;
  ushort* wihp1f = wihp0r + 524288;
  ushort* wihp1r = wihp1f + 2097152;
  ushort* whhp0f = wihp1r + 2097152;
  ushort* whhp0r = whhp0f + 1048576;
  ushort* whhp1f = whhp0r + 1048576;
  ushort* whhp1r = whhp1f + 1048576;
  float* pref = (float*)(whhp1r + 1048576);       // (8192,2048) f32
  float* prer = pref + 16777216;

  float* loss = (float*)d_out;
  float* em = (float*)d_out + 1;

  // zero the barrier slots only (h needs no init: t=0 skips the MFMA)
  hipMemsetAsync(d_ws, 0, 4096, stream);

  embed_bf16<<<2048, 256, 0, stream>>>(ids, emb, x0bf);
  conv_perm_bf16<256><<<512, 256, 0, stream>>>(wih0f, wihp0f);
  conv_perm_bf16<256><<<512, 256, 0, stream>>>(wih0r, wihp0r);
  conv_perm_bf16<1024><<<2048, 256, 0, stream>>>(wih1f, wihp1f);
  conv_perm_bf16<1024><<<2048, 256, 0, stream>>>(wih1r, wihp1r);
  conv_perm_bf16<512><<<1024, 256, 0, stream>>>(whh0f, whhp0f);
  conv_perm_bf16<512><<<1024, 256, 0, stream>>>(whh0r, whhp0r);
  conv_perm_bf16<512><<<1024, 256, 0, stream>>>(whh1f, whhp1f);
  conv_perm_bf16<512><<<1024, 256, 0, stream>>>(whh1r, whhp1r);

  // ---- layer 0 ----
  pre_gemm_mfma<256><<<dim3(64, 16), 256, 0, stream>>>(x0bf, wihp0f, bih0f, bhh0f, pref);
  pre_gemm_mfma<256><<<dim3(64, 16), 256, 0, stream>>>(x0bf, wihp0r, bih0r, bhh0r, prer);
  {
    const float* a0 = pref; const float* a1 = prer;
    const ushort* a2 = whhp0f; const ushort* a3 = whhp0r;
    ushort* a4 = xc1; int* a5 = sync0;
    void* args[] = {&a0, &a1, &a2, &a3, &a4, &a5};
    (void)hipLaunchCooperativeKernel((void*)lstm_layer_mfma, dim3(2 * NWGD), dim3(256), args, 0, stream);
  }
  // ---- layer 1 ----
  pre_gemm_mfma<1024><<<dim3(64, 16), 256, 0, stream>>>(xc1, wihp1f, bih1f, bhh1f, pref);
  pre_gemm_mfma<1024><<<dim3(64, 16), 256, 0, stream>>>(xc1, wihp1r, bih1r, bhh1r, prer);
  {
    const float* a0 = pref; const float* a1 = prer;
    const ushort* a2 = whhp1f; const ushort* a3 = whhp1r;
    ushort* a4 = xc2; int* a5 = sync1;
    void* args[] = {&a0, &a1, &a2, &a3, &a4, &a5};
    (void)hipLaunchCooperativeKernel((void*)lstm_layer_mfma, dim3(2 * NWGD), dim3(256), args, 0, stream);
  }

  cls_kernel_bf<<<(BB * TT * LL + 255) / 256, 256, 0, stream>>>(xc2, cls_w, cls_b, em);
  crf_part<<<4, 128, 0, stream>>>(em, labels, amask, crf_s, crf_e, crf_t, partials);
  crf_final<<<1, 64, 0, stream>>>(partials, loss);
}